// Round 1
// baseline (2060.978 us; speedup 1.0000x reference)
//
#include <hip/hip_runtime.h>

#define NN 60000
#define NE 300000

static inline int cdiv(int a, int b) { return (a + b - 1) / b; }

__device__ inline unsigned ord_enc(float x) {
  unsigned u = __float_as_uint(x);
  return (u & 0x80000000u) ? ~u : (u | 0x80000000u);
}
__device__ inline float ord_dec(unsigned u) {
  return __uint_as_float((u & 0x80000000u) ? (u & 0x7fffffffu) : ~u);
}

// ---------------- projections ----------------
// out[r][o] = b[o] + sum_i x[r][i] * W[i][o],  o in [0,64)
template <int IN>
__global__ void proj_kernel(const float* __restrict__ x, const float* __restrict__ W,
                            const float* __restrict__ b, float* __restrict__ out, int rows) {
  int idx = blockIdx.x * blockDim.x + threadIdx.x;
  if (idx >= rows * 64) return;
  int r = idx >> 6, o = idx & 63;
  const float* xr = x + (size_t)r * IN;
  float acc = b[o];
#pragma unroll
  for (int i = 0; i < IN; ++i) acc = fmaf(xr[i], W[i * 64 + o], acc);
  out[idx] = acc;
}

// ---------------- EGAT: node-side projections (3 GEMMs N x 64 x 64) ----------------
__global__ void hproj_kernel(const float* __restrict__ h, const float* __restrict__ wni,
                             const float* __restrict__ wnj, const float* __restrict__ wnode,
                             float* __restrict__ hs, float* __restrict__ hd,
                             float* __restrict__ hn) {
  __shared__ float s_ni[4096], s_nj[4096], s_no[4096];
  for (int i = threadIdx.x; i < 4096; i += blockDim.x) {
    s_ni[i] = wni[i]; s_nj[i] = wnj[i]; s_no[i] = wnode[i];
  }
  __syncthreads();
  int idx = blockIdx.x * blockDim.x + threadIdx.x;
  if (idx >= NN * 64) return;
  int r = idx >> 6, o = idx & 63;
  const float* hr = h + (size_t)r * 64;
  float a1 = 0.f, a2 = 0.f, a3 = 0.f;
#pragma unroll
  for (int i = 0; i < 64; ++i) {
    float hv = hr[i];
    a1 = fmaf(hv, s_ni[i * 64 + o], a1);
    a2 = fmaf(hv, s_nj[i * 64 + o], a2);
    a3 = fmaf(hv, s_no[i * 64 + o], a3);
  }
  hs[idx] = a1; hd[idx] = a2; hn[idx] = a3;
}

// ---------------- EGAT: per-edge f_out + attention logit ----------------
// one wave (64 lanes) per edge; lane = output channel o
template <bool STORE>
__global__ void fout_kernel(float* f,  // E x 64, read; written in place if STORE
                            const float* __restrict__ hs, const float* __restrict__ hd,
                            const int* __restrict__ src, const int* __restrict__ dst,
                            const float* __restrict__ fij, const float* __restrict__ attn,
                            const float* __restrict__ bias, float* __restrict__ logit,
                            unsigned* __restrict__ nmax) {
  __shared__ float s_fij[4096];
  for (int i = threadIdx.x; i < 4096; i += blockDim.x) s_fij[i] = fij[i];
  __syncthreads();
  int wave = (blockIdx.x * blockDim.x + threadIdx.x) >> 6;
  int lane = threadIdx.x & 63;
  if (wave >= NE) return;
  int s = src[wave], d = dst[wave];
  float fv = f[(size_t)wave * 64 + lane];
  float acc = hs[(size_t)s * 64 + lane] + hd[(size_t)d * 64 + lane] + bias[lane];
#pragma unroll
  for (int i = 0; i < 64; ++i)
    acc = fmaf(__shfl(fv, i, 64), s_fij[i * 64 + lane], acc);
  float fo = acc >= 0.f ? acc : 0.01f * acc;  // LeakyReLU
  if (STORE) f[(size_t)wave * 64 + lane] = fo;
  float p = fo * attn[lane];
#pragma unroll
  for (int off = 32; off; off >>= 1) p += __shfl_xor(p, off, 64);
  if (lane == 0) {
    logit[wave] = p;
    atomicMax(nmax + d, ord_enc(p));
  }
}

// ---------------- EGAT: edge softmax numerator + segment denom ----------------
__global__ void expsum_kernel(const float* __restrict__ logit, const int* __restrict__ dst,
                              const unsigned* __restrict__ nmax, float* __restrict__ wbuf,
                              float* __restrict__ nsum) {
  int e = blockIdx.x * blockDim.x + threadIdx.x;
  if (e >= NE) return;
  int d = dst[e];
  float m = ord_dec(nmax[d]);
  float w = __expf(logit[e] - m);
  wbuf[e] = w;
  atomicAdd(nsum + d, w);
}

__global__ void normw_kernel(float* __restrict__ wbuf, const int* __restrict__ dst,
                             const float* __restrict__ nsum) {
  int e = blockIdx.x * blockDim.x + threadIdx.x;
  if (e >= NE) return;
  wbuf[e] = wbuf[e] / nsum[dst[e]];
}

// ---------------- EGAT: scatter-aggregate ----------------
__global__ void aggregate_kernel(const float* __restrict__ hn, const int* __restrict__ src,
                                 const int* __restrict__ dst, const float* __restrict__ wbuf,
                                 float* __restrict__ hnew) {
  int idx = blockIdx.x * blockDim.x + threadIdx.x;
  if (idx >= NE * 64) return;
  int e = idx >> 6, o = idx & 63;
  float v = hn[(size_t)src[e] * 64 + o] * wbuf[e];
  atomicAdd(hnew + (size_t)dst[e] * 64 + o, v);
}

// ---------------- NNConv (fused, never materialize W_e) ----------------
// thread = (edge, o), o in [0,32). m[e][o] = sum_i x[i] * (nn_b[i*32+o] + sum_k ef[k]*nn_w[k][i*32+o])
__global__ void nnconv_kernel(const float* __restrict__ face, const float* __restrict__ ef,
                              const float* __restrict__ nn_w, const float* __restrict__ nn_b,
                              const int* __restrict__ src, const int* __restrict__ dst,
                              float* __restrict__ sArr, float* __restrict__ cnt) {
  __shared__ float s_w[16384];
  for (int i = threadIdx.x; i < 16384; i += blockDim.x) s_w[i] = nn_w[i];
  __syncthreads();
  int gid = blockIdx.x * blockDim.x + threadIdx.x;
  int e = gid >> 5, o = gid & 31;
  if (e >= NE) return;
  const float* efe = ef + (size_t)e * 16;
  float ek[16];
#pragma unroll
  for (int k = 0; k < 16; ++k) ek[k] = efe[k];
  const float* xr = face + (size_t)src[e] * 32;
  float acc = 0.f;
#pragma unroll 4
  for (int i = 0; i < 32; ++i) {
    float w = nn_b[i * 32 + o];
#pragma unroll
    for (int k = 0; k < 16; ++k) w = fmaf(ek[k], s_w[k * 1024 + i * 32 + o], w);
    acc = fmaf(xr[i], w, acc);
  }
  atomicAdd(sArr + (size_t)dst[e] * 32 + o, acc);
  if (o == 0) atomicAdd(cnt + dst[e], 1.0f);
}

// ---------------- combine into node_features ----------------
__global__ void combine_kernel(const float* __restrict__ hfin, const float* __restrict__ sArr,
                               const float* __restrict__ cnt, const float* __restrict__ nn_bias,
                               float* __restrict__ out) {
  int idx = blockIdx.x * blockDim.x + threadIdx.x;
  if (idx >= NN * 128) return;
  int n = idx >> 7, c = idx & 127;
  float v;
  if (c < 64) v = hfin[(size_t)n * 64 + c];
  else if (c < 96) v = sArr[(size_t)n * 32 + (c - 64)] / fmaxf(cnt[n], 1.0f) + nn_bias[c - 64];
  else v = 0.f;
  out[idx] = v;
}

// ---------------- global attention pooling ----------------
__global__ void gate_logit_kernel(const float* __restrict__ nf, const float* __restrict__ gate_w,
                                  const float* __restrict__ gate_b, float* __restrict__ g,
                                  unsigned* __restrict__ gmax) {
  int n = blockIdx.x * blockDim.x + threadIdx.x;
  float v = -3.0e38f;
  if (n < NN) {
    float acc = gate_b[0];
    const float* r = nf + (size_t)n * 128;
#pragma unroll
    for (int c = 0; c < 96; ++c) acc = fmaf(r[c], gate_w[c], acc);  // cols 96..127 are zero
    g[n] = acc;
    v = acc;
  }
#pragma unroll
  for (int off = 32; off; off >>= 1) v = fmaxf(v, __shfl_xor(v, off, 64));
  __shared__ float sm[4];
  int lane = threadIdx.x & 63, wid = threadIdx.x >> 6;
  if (lane == 0) sm[wid] = v;
  __syncthreads();
  if (threadIdx.x == 0) {
    float m = fmaxf(fmaxf(sm[0], sm[1]), fmaxf(sm[2], sm[3]));
    atomicMax(gmax, ord_enc(m));
  }
}

__global__ void gate_exp_kernel(float* __restrict__ g, const unsigned* __restrict__ gmax,
                                float* __restrict__ gsum) {
  int n = blockIdx.x * blockDim.x + threadIdx.x;
  float m = ord_dec(*gmax);
  float w = 0.f;
  if (n < NN) { w = __expf(g[n] - m); g[n] = w; }
  float v = w;
#pragma unroll
  for (int off = 32; off; off >>= 1) v += __shfl_xor(v, off, 64);
  __shared__ float sm[4];
  int lane = threadIdx.x & 63, wid = threadIdx.x >> 6;
  if (lane == 0) sm[wid] = v;
  __syncthreads();
  if (threadIdx.x == 0) atomicAdd(gsum, sm[0] + sm[1] + sm[2] + sm[3]);
}

__global__ void pool_kernel(const float* __restrict__ nf, const float* __restrict__ gw,
                            float* __restrict__ gacc) {
  int o = threadIdx.x;  // blockDim = 128
  float acc = 0.f;
  for (int n = blockIdx.x; n < NN; n += gridDim.x)
    acc += gw[n] * nf[(size_t)n * 128 + o];
  atomicAdd(gacc + o, acc);
}

__global__ void finalize_kernel(const float* __restrict__ gacc, const float* __restrict__ gsum,
                                float* __restrict__ out) {
  int o = threadIdx.x;
  if (o < 128) out[(size_t)NN * 128 + o] = gacc[o] / gsum[0];
}

extern "C" void kernel_launch(void* const* d_in, const int* in_sizes, int n_in,
                              void* d_out, int out_size, void* d_ws, size_t ws_size,
                              hipStream_t stream) {
  const float* face    = (const float*)d_in[0];
  const float* ef      = (const float*)d_in[1];
  const float* fp_w    = (const float*)d_in[2];
  const float* fp_b    = (const float*)d_in[3];
  const float* ep_w    = (const float*)d_in[4];
  const float* ep_b    = (const float*)d_in[5];
  const float* nn_w    = (const float*)d_in[6];
  const float* nn_b    = (const float*)d_in[7];
  const float* nn_bias = (const float*)d_in[8];
  const float* gate_w  = (const float*)d_in[9];
  const float* gate_b  = (const float*)d_in[10];
  const int*   src     = (const int*)d_in[11];
  const int*   dst     = (const int*)d_in[12];
  // e1: 13..18, e2: 19..24  (ni, nj, fij, node, attn, bias)
  float* out = (float*)d_out;

  char* p = (char*)d_ws;
  auto alloc = [&](size_t nfloats) {
    float* r = (float*)p;
    p += ((nfloats * 4 + 255) / 256) * 256;
    return r;
  };
  float* h0    = alloc((size_t)NN * 64);
  float* h1    = alloc((size_t)NN * 64);
  float* hs    = alloc((size_t)NN * 64);
  float* hd    = alloc((size_t)NN * 64);
  float* hn    = alloc((size_t)NN * 64);
  float* f0    = alloc((size_t)NE * 64);
  float* logit = alloc(NE);
  float* wbuf  = alloc(NE);
  unsigned* nmax = (unsigned*)alloc(NN);
  float* nsum  = alloc(NN);
  float* sArr  = alloc((size_t)NN * 32);
  float* cnt   = alloc(NN);
  float* g     = alloc(NN);
  float* gacc  = alloc(128);
  float* gsum  = alloc(1);
  unsigned* gmax = (unsigned*)alloc(1);

  const int B = 256;

  // projections
  proj_kernel<32><<<cdiv(NN * 64, B), B, 0, stream>>>(face, fp_w, fp_b, h0, NN);
  proj_kernel<16><<<cdiv(NE * 64, B), B, 0, stream>>>(ef, ep_w, ep_b, f0, NE);

  // two EGAT layers
  for (int L = 0; L < 2; ++L) {
    const float* w_ni   = (const float*)d_in[13 + 6 * L];
    const float* w_nj   = (const float*)d_in[14 + 6 * L];
    const float* w_fij  = (const float*)d_in[15 + 6 * L];
    const float* w_node = (const float*)d_in[16 + 6 * L];
    const float* attn   = (const float*)d_in[17 + 6 * L];
    const float* bias   = (const float*)d_in[18 + 6 * L];
    float* hin  = (L == 0) ? h0 : h1;
    float* hout = (L == 0) ? h1 : h0;

    hipMemsetAsync(nmax, 0, NN * 4, stream);
    hipMemsetAsync(nsum, 0, NN * 4, stream);
    hipMemsetAsync(hout, 0, (size_t)NN * 64 * 4, stream);

    hproj_kernel<<<cdiv(NN * 64, B), B, 0, stream>>>(hin, w_ni, w_nj, w_node, hs, hd, hn);
    if (L == 0)
      fout_kernel<true><<<cdiv(NE * 64, B), B, 0, stream>>>(f0, hs, hd, src, dst, w_fij, attn,
                                                            bias, logit, nmax);
    else
      fout_kernel<false><<<cdiv(NE * 64, B), B, 0, stream>>>(f0, hs, hd, src, dst, w_fij, attn,
                                                             bias, logit, nmax);
    expsum_kernel<<<cdiv(NE, B), B, 0, stream>>>(logit, dst, nmax, wbuf, nsum);
    normw_kernel<<<cdiv(NE, B), B, 0, stream>>>(wbuf, dst, nsum);
    aggregate_kernel<<<cdiv(NE * 64, B), B, 0, stream>>>(hn, src, dst, wbuf, hout);
  }

  // NNConv
  hipMemsetAsync(sArr, 0, (size_t)NN * 32 * 4, stream);
  hipMemsetAsync(cnt, 0, NN * 4, stream);
  nnconv_kernel<<<cdiv(NE * 32, B), B, 0, stream>>>(face, ef, nn_w, nn_b, src, dst, sArr, cnt);

  // combine node features (Gf | Ef | zeros)
  combine_kernel<<<cdiv(NN * 128, B), B, 0, stream>>>(h0, sArr, cnt, nn_bias, out);

  // global attention pooling
  hipMemsetAsync(gacc, 0, 128 * 4, stream);
  hipMemsetAsync(gsum, 0, 4, stream);
  hipMemsetAsync(gmax, 0, 4, stream);
  gate_logit_kernel<<<cdiv(NN, B), B, 0, stream>>>(out, gate_w, gate_b, g, gmax);
  gate_exp_kernel<<<cdiv(NN, B), B, 0, stream>>>(g, gmax, gsum);
  pool_kernel<<<512, 128, 0, stream>>>(out, g, gacc);
  finalize_kernel<<<1, 128, 0, stream>>>(gacc, gsum, out);
}

// Round 2
// 1339.440 us; speedup vs baseline: 1.5387x; 1.5387x over previous
//
#include <hip/hip_runtime.h>

#define NN 60000
#define NE 300000

static inline int cdiv(int a, int b) { return (a + b - 1) / b; }

__device__ inline unsigned ord_enc(float x) {
  unsigned u = __float_as_uint(x);
  return (u & 0x80000000u) ? ~u : (u | 0x80000000u);
}
__device__ inline float ord_dec(unsigned u) {
  return __uint_as_float((u & 0x80000000u) ? (u & 0x7fffffffu) : ~u);
}

// ---------------- generic wave-per-row matvec: out[r][o] = b[o] + sum_i x[r][i]*W[i][o]
// W column held in registers; x row broadcast via shfl. Grid-stride over rows.
template <int IN, bool BIAS>
__global__ void matvec_kernel(const float* __restrict__ x, const float* __restrict__ W,
                              const float* __restrict__ b, float* __restrict__ out, int rows) {
  int lane = threadIdx.x & 63;
  float w[IN];
#pragma unroll
  for (int i = 0; i < IN; ++i) w[i] = W[i * 64 + lane];
  float bv = BIAS ? b[lane] : 0.f;
  int wave = (blockIdx.x * blockDim.x + threadIdx.x) >> 6;
  int nw = (gridDim.x * blockDim.x) >> 6;
  for (int r = wave; r < rows; r += nw) {
    float xv = (lane < IN) ? x[(size_t)r * IN + lane] : 0.f;
    float acc = bv;
#pragma unroll
    for (int i = 0; i < IN; ++i) acc = fmaf(__shfl(xv, i, 64), w[i], acc);
    out[(size_t)r * 64 + lane] = acc;
  }
}

// ---------------- EGAT: per-edge f_out + attention logit (fij column in registers) -------
template <bool STORE>
__global__ void fout_kernel(float* __restrict__ f, const float* __restrict__ hs,
                            const float* __restrict__ hd, const int* __restrict__ src,
                            const int* __restrict__ dst, const float* __restrict__ fij,
                            const float* __restrict__ attn, const float* __restrict__ bias,
                            float* __restrict__ logit, unsigned* __restrict__ nmax) {
  int lane = threadIdx.x & 63;
  float w[64];
#pragma unroll
  for (int i = 0; i < 64; ++i) w[i] = fij[i * 64 + lane];
  float bv = bias[lane], av = attn[lane];
  int wave = (blockIdx.x * blockDim.x + threadIdx.x) >> 6;
  int nw = (gridDim.x * blockDim.x) >> 6;
  for (int e = wave; e < NE; e += nw) {
    int s = src[e], d = dst[e];
    float fv = f[(size_t)e * 64 + lane];
    float acc = hs[(size_t)s * 64 + lane] + hd[(size_t)d * 64 + lane] + bv;
#pragma unroll
    for (int i = 0; i < 64; ++i) acc = fmaf(__shfl(fv, i, 64), w[i], acc);
    float fo = acc >= 0.f ? acc : 0.01f * acc;  // LeakyReLU
    if (STORE) f[(size_t)e * 64 + lane] = fo;
    float p = fo * av;
#pragma unroll
    for (int off = 32; off; off >>= 1) p += __shfl_xor(p, off, 64);
    if (lane == 0) {
      logit[e] = p;
      atomicMax(nmax + d, ord_enc(p));
    }
  }
}

// ---------------- EGAT: edge softmax numerator + segment denom ----------------
__global__ void expsum_kernel(const float* __restrict__ logit, const int* __restrict__ dst,
                              const unsigned* __restrict__ nmax, float* __restrict__ wbuf,
                              float* __restrict__ nsum) {
  int e = blockIdx.x * blockDim.x + threadIdx.x;
  if (e >= NE) return;
  int d = dst[e];
  float m = ord_dec(nmax[d]);
  float w = __expf(logit[e] - m);
  wbuf[e] = w;
  atomicAdd(nsum + d, w);
}

__global__ void normw_kernel(float* __restrict__ wbuf, const int* __restrict__ dst,
                             const float* __restrict__ nsum) {
  int e = blockIdx.x * blockDim.x + threadIdx.x;
  if (e >= NE) return;
  wbuf[e] = wbuf[e] / nsum[dst[e]];
}

// ---------------- EGAT: scatter-aggregate ----------------
__global__ void aggregate_kernel(const float* __restrict__ hn, const int* __restrict__ src,
                                 const int* __restrict__ dst, const float* __restrict__ wbuf,
                                 float* __restrict__ hnew) {
  int idx = blockIdx.x * blockDim.x + threadIdx.x;
  if (idx >= NE * 64) return;
  int e = idx >> 6, o = idx & 63;
  float v = hn[(size_t)src[e] * 64 + o] * wbuf[e];
  atomicAdd(hnew + (size_t)dst[e] * 64 + o, v);
}

// ---------------- NNConv stage 1: per-node z = face @ nn_w, q = face @ nn_b --------------
// z[n][o*16+k] = sum_i face[n][i]*nn_w[k*1024+i*32+o]; q[n][o] = sum_i face[n][i]*nn_b[i*32+o]
// thread owns one output column (weights in 32 regs), loops over a 128-node chunk staged in LDS.
#define ZCHUNK 128
__global__ void zq_kernel(const float* __restrict__ face, const float* __restrict__ nn_w,
                          const float* __restrict__ nn_b, float* __restrict__ z,
                          float* __restrict__ q) {
  __shared__ float s_x[ZCHUNK * 32];
  int tid = threadIdx.x;
  int c = blockIdx.y * 256 + tid;  // 0..767, active < 544
  float w[32];
  float* outp = z;
  int stride = 512;
  if (c < 512) {
    int o = c >> 4, k = c & 15;
#pragma unroll
    for (int i = 0; i < 32; ++i) w[i] = nn_w[k * 1024 + i * 32 + o];
    outp = z + c;
  } else if (c < 544) {
    int o = c - 512;
#pragma unroll
    for (int i = 0; i < 32; ++i) w[i] = nn_b[i * 32 + o];
    outp = q + o;
    stride = 32;
  }
  int nbase = blockIdx.x * ZCHUNK;
  int ncnt = min(ZCHUNK, NN - nbase);
  for (int j = tid; j < ncnt * 32; j += 256) s_x[j] = face[(size_t)nbase * 32 + j];
  __syncthreads();
  if (c >= 544) return;
  for (int nl = 0; nl < ncnt; ++nl) {
    const float4* xr = (const float4*)(s_x + nl * 32);
    float acc = 0.f;
#pragma unroll
    for (int j = 0; j < 8; ++j) {
      float4 xv = xr[j];
      acc = fmaf(xv.x, w[j * 4 + 0], acc);
      acc = fmaf(xv.y, w[j * 4 + 1], acc);
      acc = fmaf(xv.z, w[j * 4 + 2], acc);
      acc = fmaf(xv.w, w[j * 4 + 3], acc);
    }
    outp[(size_t)(nbase + nl) * stride] = acc;
  }
}

// ---------------- NNConv stage 2: per-edge m[e][o] = q[s][o] + sum_k ef[e][k]*z[s][o*16+k]
__global__ void nnconv_edge_kernel(const float* __restrict__ z, const float* __restrict__ q,
                                   const float* __restrict__ ef, const int* __restrict__ src,
                                   const int* __restrict__ dst, float* __restrict__ sArr,
                                   float* __restrict__ cnt) {
  int gid = blockIdx.x * blockDim.x + threadIdx.x;
  if (gid >= NE * 32) return;
  int e = gid >> 5, o = gid & 31;
  int s = src[e], d = dst[e];
  const float4* zr = (const float4*)(z + (size_t)s * 512 + o * 16);
  const float4* er = (const float4*)(ef + (size_t)e * 16);
  float acc = q[(size_t)s * 32 + o];
#pragma unroll
  for (int j = 0; j < 4; ++j) {
    float4 zv = zr[j], ev = er[j];
    acc = fmaf(ev.x, zv.x, acc);
    acc = fmaf(ev.y, zv.y, acc);
    acc = fmaf(ev.z, zv.z, acc);
    acc = fmaf(ev.w, zv.w, acc);
  }
  atomicAdd(sArr + (size_t)d * 32 + o, acc);
  if (o == 0) atomicAdd(cnt + d, 1.0f);
}

// ---------------- combine into node_features ----------------
__global__ void combine_kernel(const float* __restrict__ hfin, const float* __restrict__ sArr,
                               const float* __restrict__ cnt, const float* __restrict__ nn_bias,
                               float* __restrict__ out) {
  int idx = blockIdx.x * blockDim.x + threadIdx.x;
  if (idx >= NN * 128) return;
  int n = idx >> 7, c = idx & 127;
  float v;
  if (c < 64) v = hfin[(size_t)n * 64 + c];
  else if (c < 96) v = sArr[(size_t)n * 32 + (c - 64)] / fmaxf(cnt[n], 1.0f) + nn_bias[c - 64];
  else v = 0.f;
  out[idx] = v;
}

// ---------------- global attention pooling ----------------
__global__ void gate_logit_kernel(const float* __restrict__ nf, const float* __restrict__ gate_w,
                                  const float* __restrict__ gate_b, float* __restrict__ g,
                                  unsigned* __restrict__ gmax) {
  int n = blockIdx.x * blockDim.x + threadIdx.x;
  float v = -3.0e38f;
  if (n < NN) {
    float acc = gate_b[0];
    const float* r = nf + (size_t)n * 128;
#pragma unroll
    for (int c = 0; c < 96; ++c) acc = fmaf(r[c], gate_w[c], acc);  // cols 96..127 are zero
    g[n] = acc;
    v = acc;
  }
#pragma unroll
  for (int off = 32; off; off >>= 1) v = fmaxf(v, __shfl_xor(v, off, 64));
  __shared__ float sm[4];
  int lane = threadIdx.x & 63, wid = threadIdx.x >> 6;
  if (lane == 0) sm[wid] = v;
  __syncthreads();
  if (threadIdx.x == 0) {
    float m = fmaxf(fmaxf(sm[0], sm[1]), fmaxf(sm[2], sm[3]));
    atomicMax(gmax, ord_enc(m));
  }
}

__global__ void gate_exp_kernel(float* __restrict__ g, const unsigned* __restrict__ gmax,
                                float* __restrict__ gsum) {
  int n = blockIdx.x * blockDim.x + threadIdx.x;
  float m = ord_dec(*gmax);
  float w = 0.f;
  if (n < NN) { w = __expf(g[n] - m); g[n] = w; }
  float v = w;
#pragma unroll
  for (int off = 32; off; off >>= 1) v += __shfl_xor(v, off, 64);
  __shared__ float sm[4];
  int lane = threadIdx.x & 63, wid = threadIdx.x >> 6;
  if (lane == 0) sm[wid] = v;
  __syncthreads();
  if (threadIdx.x == 0) atomicAdd(gsum, sm[0] + sm[1] + sm[2] + sm[3]);
}

__global__ void pool_kernel(const float* __restrict__ nf, const float* __restrict__ gw,
                            float* __restrict__ gacc) {
  int o = threadIdx.x;  // blockDim = 128
  float acc = 0.f;
  for (int n = blockIdx.x; n < NN; n += gridDim.x)
    acc += gw[n] * nf[(size_t)n * 128 + o];
  atomicAdd(gacc + o, acc);
}

__global__ void finalize_kernel(const float* __restrict__ gacc, const float* __restrict__ gsum,
                                float* __restrict__ out) {
  int o = threadIdx.x;
  if (o < 128) out[(size_t)NN * 128 + o] = gacc[o] / gsum[0];
}

extern "C" void kernel_launch(void* const* d_in, const int* in_sizes, int n_in,
                              void* d_out, int out_size, void* d_ws, size_t ws_size,
                              hipStream_t stream) {
  const float* face    = (const float*)d_in[0];
  const float* ef      = (const float*)d_in[1];
  const float* fp_w    = (const float*)d_in[2];
  const float* fp_b    = (const float*)d_in[3];
  const float* ep_w    = (const float*)d_in[4];
  const float* ep_b    = (const float*)d_in[5];
  const float* nn_w    = (const float*)d_in[6];
  const float* nn_b    = (const float*)d_in[7];
  const float* nn_bias = (const float*)d_in[8];
  const float* gate_w  = (const float*)d_in[9];
  const float* gate_b  = (const float*)d_in[10];
  const int*   src     = (const int*)d_in[11];
  const int*   dst     = (const int*)d_in[12];
  float* out = (float*)d_out;

  char* p = (char*)d_ws;
  auto alloc = [&](size_t nfloats) {
    float* r = (float*)p;
    p += ((nfloats * 4 + 255) / 256) * 256;
    return r;
  };
  float* h0 = alloc((size_t)NN * 64);
  float* h1 = alloc((size_t)NN * 64);       // dead after EGAT layer 2 -> q aliases here
  char* regionC = p;                        // hs|hd|hn|f0 = 122.88 MB, dead after EGAT
  float* hs    = alloc((size_t)NN * 64);
  float* hd    = alloc((size_t)NN * 64);
  float* hn    = alloc((size_t)NN * 64);
  float* f0    = alloc((size_t)NE * 64);
  float* logit = alloc(NE);
  float* wbuf  = alloc(NE);
  unsigned* nmax = (unsigned*)alloc(NN);
  float* nsum  = alloc(NN);
  float* sArr  = alloc((size_t)NN * 32);
  float* cnt   = alloc(NN);
  float* g     = alloc(NN);
  float* gacc  = alloc(128);
  float* gsum  = alloc(1);
  unsigned* gmax = (unsigned*)alloc(1);
  float* z = (float*)regionC;               // NN*512 floats = exactly hs+hd+hn+f0
  float* q = h1;                            // NN*32 floats <= h1's NN*64

  const int B = 256;

  // projections (register-column matvec)
  matvec_kernel<32, true><<<1024, B, 0, stream>>>(face, fp_w, fp_b, h0, NN);
  matvec_kernel<16, true><<<2048, B, 0, stream>>>(ef, ep_w, ep_b, f0, NE);

  // two EGAT layers
  for (int L = 0; L < 2; ++L) {
    const float* w_ni   = (const float*)d_in[13 + 6 * L];
    const float* w_nj   = (const float*)d_in[14 + 6 * L];
    const float* w_fij  = (const float*)d_in[15 + 6 * L];
    const float* w_node = (const float*)d_in[16 + 6 * L];
    const float* attn   = (const float*)d_in[17 + 6 * L];
    const float* bias   = (const float*)d_in[18 + 6 * L];
    float* hin  = (L == 0) ? h0 : h1;
    float* hout = (L == 0) ? h1 : h0;

    hipMemsetAsync(nmax, 0, NN * 4, stream);
    hipMemsetAsync(nsum, 0, NN * 4, stream);
    hipMemsetAsync(hout, 0, (size_t)NN * 64 * 4, stream);

    matvec_kernel<64, false><<<1024, B, 0, stream>>>(hin, w_ni, nullptr, hs, NN);
    matvec_kernel<64, false><<<1024, B, 0, stream>>>(hin, w_nj, nullptr, hd, NN);
    matvec_kernel<64, false><<<1024, B, 0, stream>>>(hin, w_node, nullptr, hn, NN);
    if (L == 0)
      fout_kernel<true><<<2048, B, 0, stream>>>(f0, hs, hd, src, dst, w_fij, attn, bias,
                                                logit, nmax);
    else
      fout_kernel<false><<<2048, B, 0, stream>>>(f0, hs, hd, src, dst, w_fij, attn, bias,
                                                 logit, nmax);
    expsum_kernel<<<cdiv(NE, B), B, 0, stream>>>(logit, dst, nmax, wbuf, nsum);
    normw_kernel<<<cdiv(NE, B), B, 0, stream>>>(wbuf, dst, nsum);
    aggregate_kernel<<<cdiv(NE * 64, B), B, 0, stream>>>(hn, src, dst, wbuf, hout);
  }

  // NNConv (two-stage; z/q alias dead EGAT buffers — must run after the loop above)
  hipMemsetAsync(sArr, 0, (size_t)NN * 32 * 4, stream);
  hipMemsetAsync(cnt, 0, NN * 4, stream);
  {
    dim3 zg(cdiv(NN, ZCHUNK), 3);
    zq_kernel<<<zg, B, 0, stream>>>(face, nn_w, nn_b, z, q);
  }
  nnconv_edge_kernel<<<cdiv(NE * 32, B), B, 0, stream>>>(z, q, ef, src, dst, sArr, cnt);

  // combine node features (Gf | Ef | zeros)
  combine_kernel<<<cdiv(NN * 128, B), B, 0, stream>>>(h0, sArr, cnt, nn_bias, out);

  // global attention pooling
  hipMemsetAsync(gacc, 0, 128 * 4, stream);
  hipMemsetAsync(gsum, 0, 4, stream);
  hipMemsetAsync(gmax, 0, 4, stream);
  gate_logit_kernel<<<cdiv(NN, B), B, 0, stream>>>(out, gate_w, gate_b, g, gmax);
  gate_exp_kernel<<<cdiv(NN, B), B, 0, stream>>>(g, gmax, gsum);
  pool_kernel<<<512, 128, 0, stream>>>(out, g, gacc);
  finalize_kernel<<<1, 128, 0, stream>>>(gacc, gsum, out);
}

// Round 3
// 1228.608 us; speedup vs baseline: 1.6775x; 1.0902x over previous
//
#include <hip/hip_runtime.h>

#define NN 60000
#define NE 300000

static inline int cdiv(int a, int b) { return (a + b - 1) / b; }

__device__ inline unsigned ord_enc(float x) {
  unsigned u = __float_as_uint(x);
  return (u & 0x80000000u) ? ~u : (u | 0x80000000u);
}
__device__ inline float ord_dec(unsigned u) {
  return __uint_as_float((u & 0x80000000u) ? (u & 0x7fffffffu) : ~u);
}
// force wave-uniform pointer so row loads become broadcast/scalar loads (no readlane chain)
__device__ inline const float* uniform_ptr(const float* p) {
  unsigned long long v = (unsigned long long)p;
  unsigned lo = __builtin_amdgcn_readfirstlane((unsigned)v);
  unsigned hi = __builtin_amdgcn_readfirstlane((unsigned)(v >> 32));
  return (const float*)(((unsigned long long)hi << 32) | lo);
}

// ---------------- fold: precompute folded weight products (7424 dots of length 64) -------
// layout (floats): [0,1024) Wf1[k<16][o]   = sum_i ep_w[k][i] * e1_fij[i][o]
//                  [1024,1088) b1f[o]      = e1_bias[o] + sum_i ep_b[i]*e1_fij[i][o]
//                  [1088,3136) Wni1[c<32][o] = sum_i fp_w[c][i]*e1_ni[i][o]
//                  [3136,5184) Wnj1        (fp_w @ e1_nj)
//                  [5184,7232) Wno1        (fp_w @ e1_node)
//                  [7232,7296) bni1[o] = fp_b @ e1_ni ; [7296,7360) bnj1 ; [7360,7424) bno1
__global__ void fold_kernel(const float* __restrict__ fp_w, const float* __restrict__ fp_b,
                            const float* __restrict__ ep_w, const float* __restrict__ ep_b,
                            const float* __restrict__ fij, const float* __restrict__ ebias,
                            const float* __restrict__ ni, const float* __restrict__ nj,
                            const float* __restrict__ node, float* __restrict__ fold) {
  int t = blockIdx.x * blockDim.x + threadIdx.x;
  if (t >= 7424) return;
  int o = t & 63;
  const float* A;
  const float* B;
  float init = 0.f;
  if (t < 1024)      { A = ep_w + (size_t)(t >> 6) * 64; B = fij + o; }
  else if (t < 1088) { A = ep_b; B = fij + o; init = ebias[o]; }
  else if (t < 3136) { A = fp_w + (size_t)((t - 1088) >> 6) * 64; B = ni + o; }
  else if (t < 5184) { A = fp_w + (size_t)((t - 3136) >> 6) * 64; B = nj + o; }
  else if (t < 7232) { A = fp_w + (size_t)((t - 5184) >> 6) * 64; B = node + o; }
  else if (t < 7296) { A = fp_b; B = ni + o; }
  else if (t < 7360) { A = fp_b; B = nj + o; }
  else               { A = fp_b; B = node + o; }
  float a = init;
  for (int i = 0; i < 64; ++i) a = fmaf(A[i], B[(size_t)i * 64], a);
  fold[t] = a;
}

// ---------------- merged 3-way matvec: o{a,b,c}[r][o] = b{a,b,c}[o] + sum_i x[r][i]*W{a,b,c}[i][o]
template <int IN, bool BIAS>
__global__ void hproj3_kernel(const float* __restrict__ x, const float* __restrict__ Wa,
                              const float* __restrict__ Wb, const float* __restrict__ Wc,
                              const float* __restrict__ ba, const float* __restrict__ bb,
                              const float* __restrict__ bc, float* __restrict__ oa,
                              float* __restrict__ ob, float* __restrict__ oc, int rows) {
  int lane = threadIdx.x & 63;
  float wa[IN], wb[IN], wc[IN];
#pragma unroll
  for (int i = 0; i < IN; ++i) {
    wa[i] = Wa[(size_t)i * 64 + lane];
    wb[i] = Wb[(size_t)i * 64 + lane];
    wc[i] = Wc[(size_t)i * 64 + lane];
  }
  float bav = BIAS ? ba[lane] : 0.f;
  float bbv = BIAS ? bb[lane] : 0.f;
  float bcv = BIAS ? bc[lane] : 0.f;
  int wave = (blockIdx.x * blockDim.x + threadIdx.x) >> 6;
  int nw = (gridDim.x * blockDim.x) >> 6;
  for (int r = wave; r < rows; r += nw) {
    const float4* xr = (const float4*)uniform_ptr(x + (size_t)r * IN);
    float a0 = bav, a1 = 0.f, a2 = 0.f, a3 = 0.f;
    float b0 = bbv, b1 = 0.f, b2 = 0.f, b3 = 0.f;
    float c0 = bcv, c1 = 0.f, c2 = 0.f, c3 = 0.f;
#pragma unroll
    for (int j = 0; j < IN / 4; ++j) {
      float4 xv = xr[j];
      a0 = fmaf(xv.x, wa[4 * j + 0], a0);
      a1 = fmaf(xv.y, wa[4 * j + 1], a1);
      a2 = fmaf(xv.z, wa[4 * j + 2], a2);
      a3 = fmaf(xv.w, wa[4 * j + 3], a3);
      b0 = fmaf(xv.x, wb[4 * j + 0], b0);
      b1 = fmaf(xv.y, wb[4 * j + 1], b1);
      b2 = fmaf(xv.z, wb[4 * j + 2], b2);
      b3 = fmaf(xv.w, wb[4 * j + 3], b3);
      c0 = fmaf(xv.x, wc[4 * j + 0], c0);
      c1 = fmaf(xv.y, wc[4 * j + 1], c1);
      c2 = fmaf(xv.z, wc[4 * j + 2], c2);
      c3 = fmaf(xv.w, wc[4 * j + 3], c3);
    }
    oa[(size_t)r * 64 + lane] = (a0 + a1) + (a2 + a3);
    ob[(size_t)r * 64 + lane] = (b0 + b1) + (b2 + b3);
    oc[(size_t)r * 64 + lane] = (c0 + c1) + (c2 + c3);
  }
}

// ---------------- EGAT: per-edge f_out + attention logit ----------------
// wave per edge; f-row via uniform loads (no shfl chain); 4 accumulators.
template <int KW, bool STORE>
__global__ void fout_kernel(const float* __restrict__ fin, const float* __restrict__ hs,
                            const float* __restrict__ hd, const int* __restrict__ src,
                            const int* __restrict__ dst, const float* __restrict__ W,
                            const float* __restrict__ attn, const float* __restrict__ bias,
                            float* __restrict__ fstore, float* __restrict__ logit,
                            unsigned* __restrict__ nmax) {
  int lane = threadIdx.x & 63;
  float w[KW];
#pragma unroll
  for (int i = 0; i < KW; ++i) w[i] = W[(size_t)i * 64 + lane];
  float bv = bias[lane], av = attn[lane];
  int wave = (blockIdx.x * blockDim.x + threadIdx.x) >> 6;
  int nw = (gridDim.x * blockDim.x) >> 6;
  for (int e = wave; e < NE; e += nw) {
    int s = src[e], d = dst[e];
    float hsv = hs[(size_t)s * 64 + lane];
    float hdv = hd[(size_t)d * 64 + lane];
    const float4* fr = (const float4*)uniform_ptr(fin + (size_t)e * KW);
    float a0 = 0.f, a1 = 0.f, a2 = 0.f, a3 = 0.f;
#pragma unroll
    for (int j = 0; j < KW / 4; ++j) {
      float4 fv = fr[j];
      a0 = fmaf(fv.x, w[4 * j + 0], a0);
      a1 = fmaf(fv.y, w[4 * j + 1], a1);
      a2 = fmaf(fv.z, w[4 * j + 2], a2);
      a3 = fmaf(fv.w, w[4 * j + 3], a3);
    }
    float acc = ((a0 + a1) + (a2 + a3)) + hsv + hdv + bv;
    float fo = acc >= 0.f ? acc : 0.01f * acc;  // LeakyReLU
    if (STORE) fstore[(size_t)e * 64 + lane] = fo;
    float p = fo * av;
#pragma unroll
    for (int off = 32; off; off >>= 1) p += __shfl_xor(p, off, 64);
    if (lane == 0) {
      logit[e] = p;
      atomicMax(nmax + d, ord_enc(p));
    }
  }
}

// ---------------- EGAT: edge softmax numerator + segment denom ----------------
__global__ void expsum_kernel(const float* __restrict__ logit, const int* __restrict__ dst,
                              const unsigned* __restrict__ nmax, float* __restrict__ wbuf,
                              float* __restrict__ nsum) {
  int e = blockIdx.x * blockDim.x + threadIdx.x;
  if (e >= NE) return;
  int d = dst[e];
  float m = ord_dec(nmax[d]);
  float w = __expf(logit[e] - m);
  wbuf[e] = w;
  atomicAdd(nsum + d, w);
}

__global__ void normw_kernel(float* __restrict__ wbuf, const int* __restrict__ dst,
                             const float* __restrict__ nsum) {
  int e = blockIdx.x * blockDim.x + threadIdx.x;
  if (e >= NE) return;
  wbuf[e] = wbuf[e] / nsum[dst[e]];
}

// ---------------- EGAT: scatter-aggregate ----------------
__global__ void aggregate_kernel(const float* __restrict__ hn, const int* __restrict__ src,
                                 const int* __restrict__ dst, const float* __restrict__ wbuf,
                                 float* __restrict__ hnew) {
  int idx = blockIdx.x * blockDim.x + threadIdx.x;
  if (idx >= NE * 64) return;
  int e = idx >> 6, o = idx & 63;
  float v = hn[(size_t)src[e] * 64 + o] * wbuf[e];
  atomicAdd(hnew + (size_t)dst[e] * 64 + o, v);
}

// ---------------- NNConv stage 1: per-node z = face @ nn_w, q = face @ nn_b --------------
#define ZCHUNK 128
__global__ void zq_kernel(const float* __restrict__ face, const float* __restrict__ nn_w,
                          const float* __restrict__ nn_b, float* __restrict__ z,
                          float* __restrict__ q) {
  __shared__ float s_x[ZCHUNK * 32];
  int tid = threadIdx.x;
  int c = blockIdx.y * 256 + tid;  // 0..767, active < 544
  float w[32];
  float* outp = z;
  int stride = 512;
  if (c < 512) {
    int o = c >> 4, k = c & 15;
#pragma unroll
    for (int i = 0; i < 32; ++i) w[i] = nn_w[(size_t)k * 1024 + i * 32 + o];
    outp = z + c;
  } else if (c < 544) {
    int o = c - 512;
#pragma unroll
    for (int i = 0; i < 32; ++i) w[i] = nn_b[(size_t)i * 32 + o];
    outp = q + o;
    stride = 32;
  }
  int nbase = blockIdx.x * ZCHUNK;
  int ncnt = min(ZCHUNK, NN - nbase);
  for (int j = tid; j < ncnt * 32; j += 256) s_x[j] = face[(size_t)nbase * 32 + j];
  __syncthreads();
  if (c >= 544) return;
  for (int nl = 0; nl < ncnt; ++nl) {
    const float4* xr = (const float4*)(s_x + nl * 32);
    float acc = 0.f;
#pragma unroll
    for (int j = 0; j < 8; ++j) {
      float4 xv = xr[j];
      acc = fmaf(xv.x, w[j * 4 + 0], acc);
      acc = fmaf(xv.y, w[j * 4 + 1], acc);
      acc = fmaf(xv.z, w[j * 4 + 2], acc);
      acc = fmaf(xv.w, w[j * 4 + 3], acc);
    }
    outp[(size_t)(nbase + nl) * stride] = acc;
  }
}

// ---------------- NNConv stage 2: per-edge m[e][o] = q[s][o] + sum_k ef[e][k]*z[s][o*16+k]
__global__ void nnconv_edge_kernel(const float* __restrict__ z, const float* __restrict__ q,
                                   const float* __restrict__ ef, const int* __restrict__ src,
                                   const int* __restrict__ dst, float* __restrict__ sArr,
                                   float* __restrict__ cnt) {
  int gid = blockIdx.x * blockDim.x + threadIdx.x;
  if (gid >= NE * 32) return;
  int e = gid >> 5, o = gid & 31;
  int s = src[e], d = dst[e];
  const float4* zr = (const float4*)(z + (size_t)s * 512 + o * 16);
  const float4* er = (const float4*)(ef + (size_t)e * 16);
  float acc = q[(size_t)s * 32 + o];
#pragma unroll
  for (int j = 0; j < 4; ++j) {
    float4 zv = zr[j], ev = er[j];
    acc = fmaf(ev.x, zv.x, acc);
    acc = fmaf(ev.y, zv.y, acc);
    acc = fmaf(ev.z, zv.z, acc);
    acc = fmaf(ev.w, zv.w, acc);
  }
  atomicAdd(sArr + (size_t)d * 32 + o, acc);
  if (o == 0) atomicAdd(cnt + d, 1.0f);
}

// ---------------- combine into node_features ----------------
__global__ void combine_kernel(const float* __restrict__ hfin, const float* __restrict__ sArr,
                               const float* __restrict__ cnt, const float* __restrict__ nn_bias,
                               float* __restrict__ out) {
  int idx = blockIdx.x * blockDim.x + threadIdx.x;
  if (idx >= NN * 128) return;
  int n = idx >> 7, c = idx & 127;
  float v;
  if (c < 64) v = hfin[(size_t)n * 64 + c];
  else if (c < 96) v = sArr[(size_t)n * 32 + (c - 64)] / fmaxf(cnt[n], 1.0f) + nn_bias[c - 64];
  else v = 0.f;
  out[idx] = v;
}

// ---------------- global attention pooling ----------------
__global__ void gate_logit_kernel(const float* __restrict__ nf, const float* __restrict__ gate_w,
                                  const float* __restrict__ gate_b, float* __restrict__ g,
                                  unsigned* __restrict__ gmax) {
  int n = blockIdx.x * blockDim.x + threadIdx.x;
  float v = -3.0e38f;
  if (n < NN) {
    float acc = gate_b[0];
    const float* r = nf + (size_t)n * 128;
#pragma unroll
    for (int c = 0; c < 96; ++c) acc = fmaf(r[c], gate_w[c], acc);  // cols 96..127 are zero
    g[n] = acc;
    v = acc;
  }
#pragma unroll
  for (int off = 32; off; off >>= 1) v = fmaxf(v, __shfl_xor(v, off, 64));
  __shared__ float sm[4];
  int lane = threadIdx.x & 63, wid = threadIdx.x >> 6;
  if (lane == 0) sm[wid] = v;
  __syncthreads();
  if (threadIdx.x == 0) {
    float m = fmaxf(fmaxf(sm[0], sm[1]), fmaxf(sm[2], sm[3]));
    atomicMax(gmax, ord_enc(m));
  }
}

__global__ void gate_exp_kernel(float* __restrict__ g, const unsigned* __restrict__ gmax,
                                float* __restrict__ gsum) {
  int n = blockIdx.x * blockDim.x + threadIdx.x;
  float m = ord_dec(*gmax);
  float w = 0.f;
  if (n < NN) { w = __expf(g[n] - m); g[n] = w; }
  float v = w;
#pragma unroll
  for (int off = 32; off; off >>= 1) v += __shfl_xor(v, off, 64);
  __shared__ float sm[4];
  int lane = threadIdx.x & 63, wid = threadIdx.x >> 6;
  if (lane == 0) sm[wid] = v;
  __syncthreads();
  if (threadIdx.x == 0) atomicAdd(gsum, sm[0] + sm[1] + sm[2] + sm[3]);
}

__global__ void pool_kernel(const float* __restrict__ nf, const float* __restrict__ gw,
                            float* __restrict__ gacc) {
  int o = threadIdx.x;  // blockDim = 128
  float acc = 0.f;
  for (int n = blockIdx.x; n < NN; n += gridDim.x)
    acc += gw[n] * nf[(size_t)n * 128 + o];
  atomicAdd(gacc + o, acc);
}

__global__ void finalize_kernel(const float* __restrict__ gacc, const float* __restrict__ gsum,
                                float* __restrict__ out) {
  int o = threadIdx.x;
  if (o < 128) out[(size_t)NN * 128 + o] = gacc[o] / gsum[0];
}

extern "C" void kernel_launch(void* const* d_in, const int* in_sizes, int n_in,
                              void* d_out, int out_size, void* d_ws, size_t ws_size,
                              hipStream_t stream) {
  const float* face    = (const float*)d_in[0];
  const float* ef      = (const float*)d_in[1];
  const float* fp_w    = (const float*)d_in[2];
  const float* fp_b    = (const float*)d_in[3];
  const float* ep_w    = (const float*)d_in[4];
  const float* ep_b    = (const float*)d_in[5];
  const float* nn_w    = (const float*)d_in[6];
  const float* nn_b    = (const float*)d_in[7];
  const float* nn_bias = (const float*)d_in[8];
  const float* gate_w  = (const float*)d_in[9];
  const float* gate_b  = (const float*)d_in[10];
  const int*   src     = (const int*)d_in[11];
  const int*   dst     = (const int*)d_in[12];
  const float* e1_ni   = (const float*)d_in[13];
  const float* e1_nj   = (const float*)d_in[14];
  const float* e1_fij  = (const float*)d_in[15];
  const float* e1_node = (const float*)d_in[16];
  const float* e1_attn = (const float*)d_in[17];
  const float* e1_bias = (const float*)d_in[18];
  const float* e2_ni   = (const float*)d_in[19];
  const float* e2_nj   = (const float*)d_in[20];
  const float* e2_fij  = (const float*)d_in[21];
  const float* e2_node = (const float*)d_in[22];
  const float* e2_attn = (const float*)d_in[23];
  const float* e2_bias = (const float*)d_in[24];
  float* out = (float*)d_out;

  char* p = (char*)d_ws;
  auto alloc = [&](size_t nfloats) {
    float* r = (float*)p;
    p += ((nfloats * 4 + 255) / 256) * 256;
    return r;
  };
  float* h0 = alloc((size_t)NN * 64);   // layer-2 output
  float* h1 = alloc((size_t)NN * 64);   // layer-1 output; q aliases after EGAT
  char* regionC = p;                    // hs|hd|hn|f1 = 122.88 MB, dead after EGAT
  float* hs    = alloc((size_t)NN * 64);
  float* hd    = alloc((size_t)NN * 64);
  float* hn    = alloc((size_t)NN * 64);
  float* f1    = alloc((size_t)NE * 64);
  float* logit = alloc(NE);
  float* wbuf  = alloc(NE);
  unsigned* nmax = (unsigned*)alloc(NN);
  float* nsum  = alloc(NN);
  float* sArr  = alloc((size_t)NN * 32);
  float* cnt   = alloc(NN);
  float* g     = alloc(NN);
  float* gacc  = alloc(128);
  float* gsum  = alloc(1);
  unsigned* gmax = (unsigned*)alloc(1);
  float* fold  = alloc(7424);
  float* z = (float*)regionC;           // NN*512 floats == hs+hd+hn+f1 region
  float* q = h1;                        // NN*32 <= h1's NN*64, h1 dead post-EGAT

  const float* Wf1  = fold;
  const float* b1f  = fold + 1024;
  const float* Wni1 = fold + 1088;
  const float* Wnj1 = fold + 3136;
  const float* Wno1 = fold + 5184;
  const float* bni1 = fold + 7232;
  const float* bnj1 = fold + 7296;
  const float* bno1 = fold + 7360;

  const int B = 256;

  // folded weights (tiny)
  fold_kernel<<<29, B, 0, stream>>>(fp_w, fp_b, ep_w, ep_b, e1_fij, e1_bias,
                                    e1_ni, e1_nj, e1_node, fold);

  // ---- EGAT layer 1 (face-level folds: h0/f0 never materialized) ----
  hipMemsetAsync(nmax, 0, NN * 4, stream);
  hipMemsetAsync(nsum, 0, NN * 4, stream);
  hipMemsetAsync(h1, 0, (size_t)NN * 64 * 4, stream);
  hproj3_kernel<32, true><<<1024, B, 0, stream>>>(face, Wni1, Wnj1, Wno1, bni1, bnj1, bno1,
                                                  hs, hd, hn, NN);
  fout_kernel<16, true><<<2048, B, 0, stream>>>(ef, hs, hd, src, dst, Wf1, e1_attn, b1f,
                                                f1, logit, nmax);
  expsum_kernel<<<cdiv(NE, B), B, 0, stream>>>(logit, dst, nmax, wbuf, nsum);
  normw_kernel<<<cdiv(NE, B), B, 0, stream>>>(wbuf, dst, nsum);
  aggregate_kernel<<<cdiv(NE * 64, B), B, 0, stream>>>(hn, src, dst, wbuf, h1);

  // ---- EGAT layer 2 ----
  hipMemsetAsync(nmax, 0, NN * 4, stream);
  hipMemsetAsync(nsum, 0, NN * 4, stream);
  hipMemsetAsync(h0, 0, (size_t)NN * 64 * 4, stream);
  hproj3_kernel<64, false><<<1024, B, 0, stream>>>(h1, e2_ni, e2_nj, e2_node, nullptr, nullptr,
                                                   nullptr, hs, hd, hn, NN);
  fout_kernel<64, false><<<2048, B, 0, stream>>>(f1, hs, hd, src, dst, e2_fij, e2_attn, e2_bias,
                                                 nullptr, logit, nmax);
  expsum_kernel<<<cdiv(NE, B), B, 0, stream>>>(logit, dst, nmax, wbuf, nsum);
  normw_kernel<<<cdiv(NE, B), B, 0, stream>>>(wbuf, dst, nsum);
  aggregate_kernel<<<cdiv(NE * 64, B), B, 0, stream>>>(hn, src, dst, wbuf, h0);

  // ---- NNConv (z/q alias dead EGAT buffers — must run after the loop above) ----
  hipMemsetAsync(sArr, 0, (size_t)NN * 32 * 4, stream);
  hipMemsetAsync(cnt, 0, NN * 4, stream);
  {
    dim3 zg(cdiv(NN, ZCHUNK), 3);
    zq_kernel<<<zg, B, 0, stream>>>(face, nn_w, nn_b, z, q);
  }
  nnconv_edge_kernel<<<cdiv(NE * 32, B), B, 0, stream>>>(z, q, ef, src, dst, sArr, cnt);

  // ---- combine node features (Gf | Ef | zeros) ----
  combine_kernel<<<cdiv(NN * 128, B), B, 0, stream>>>(h0, sArr, cnt, nn_bias, out);

  // ---- global attention pooling ----
  hipMemsetAsync(gacc, 0, 128 * 4, stream);
  hipMemsetAsync(gsum, 0, 4, stream);
  hipMemsetAsync(gmax, 0, 4, stream);
  gate_logit_kernel<<<cdiv(NN, B), B, 0, stream>>>(out, gate_w, gate_b, g, gmax);
  gate_exp_kernel<<<cdiv(NN, B), B, 0, stream>>>(g, gmax, gsum);
  pool_kernel<<<512, 128, 0, stream>>>(out, g, gacc);
  finalize_kernel<<<1, 128, 0, stream>>>(gacc, gsum, out);
}